// Round 12
// baseline (163.769 us; speedup 1.0000x reference)
//
#include <hip/hip_runtime.h>
#include <hip/hip_bf16.h>
#include <math.h>

#define NB 16
#define NT 2048
#define ND 512
#define NH 64

typedef __attribute__((ext_vector_type(8))) short short8;
typedef __attribute__((ext_vector_type(4))) float float4v;

__device__ __forceinline__ bool mask_is_bytes(const int* m) {
    return m[0] == 0x01010101;
}
__device__ __forceinline__ bool mask_at(const int* m, bool bytes, int i) {
    if (bytes) return ((const unsigned char*)m)[i] != 0;
    return m[i] != 0;
}

// Minkowski dot, metric folded into `a`; explicit fmaf so pass 1 / pass 2
// recompute bitwise-identical values.
__device__ __forceinline__ float dot4(float4 a, float4 p) {
    float d = a.x * p.x;
    d = __builtin_fmaf(a.y, p.y, d);
    d = __builtin_fmaf(a.z, p.z, d);
    d = __builtin_fmaf(a.w, p.w, d);
    return d;
}

__device__ __forceinline__ unsigned short f2bf(float x) {
    unsigned int u = __float_as_uint(x);
    u += 0x7fffu + ((u >> 16) & 1u);
    return (unsigned short)(u >> 16);
}

// 8-slot sorted-descending insert via med3 chain (exact no-op when D < V7).
#define INS8(V0,V1,V2,V3,V4,V5,V6,V7,D)                          \
    {                                                            \
        float n0 = fmaxf(V0, D);                                 \
        float n1 = __builtin_amdgcn_fmed3f(D, V0, V1);           \
        float n2 = __builtin_amdgcn_fmed3f(D, V1, V2);           \
        float n3 = __builtin_amdgcn_fmed3f(D, V2, V3);           \
        float n4 = __builtin_amdgcn_fmed3f(D, V3, V4);           \
        float n5 = __builtin_amdgcn_fmed3f(D, V4, V5);           \
        float n6 = __builtin_amdgcn_fmed3f(D, V5, V6);           \
        float n7 = __builtin_amdgcn_fmed3f(D, V6, V7);           \
        V0 = n0; V1 = n1; V2 = n2; V3 = n3;                      \
        V4 = n4; V5 = n5; V6 = n6; V7 = n7;                      \
    }

// ---------------------------------------------------------------------------
// Kernel A (proven R4): tokens -> P in GLOBAL ws (masked = (-1e30,0,0,0)),
// plus one-time W2 fp32[k][n] -> bf16 W2t[n][k].
// ---------------------------------------------------------------------------
__global__ void __launch_bounds__(256) compute_P_kernel(
        const float* __restrict__ tok,
        const int* __restrict__ mask,
        float4* __restrict__ P,
        unsigned short* __restrict__ W2t,
        const float* __restrict__ W2) {
    const bool mb = mask_is_bytes(mask);
    int i = blockIdx.x * 256 + threadIdx.x;

    float4 t = ((const float4*)tok)[i];
    float E = t.x, Pt = t.y, eta = t.z, phi = t.w;
    float px = Pt * cosf(phi);
    float py = Pt * sinf(phi);
    float pz = Pt * sinhf(fminf(fmaxf(eta, -20.f), 20.f));
    bool m = mask_at(mask, mb, i);
    P[i] = m ? make_float4(E, px, py, pz)
             : make_float4(-1e30f, 0.f, 0.f, 0.f);

    int n = i & 511, k = i >> 9;
    W2t[n * NH + k] = f2bf(W2[k * ND + n]);
}

// ---------------------------------------------------------------------------
// Kernel B: fused, LDS-FREE hot loop + full occupancy.
// 1024 thr = 16 waves, 64 tokens/block (lane = token), chunk = L/16.
// Scan reads P from GLOBAL with wave-uniform s (scalar/L1 path — no LDS
// pipe, no staging). Grid 512 -> 2 blocks/CU -> 32 waves/CU (HW max).
// Wave 0 merges 16x8 candidates -> th2/4/8 broadcast via LDS.
// LDS ~61 KB: scratch union (vtop 32K / psum 48K) + hs + th/mass.
// ---------------------------------------------------------------------------
#define VT(w2, j, l)  scratch[((w2) * 8 + (j)) * 64 + (l)]    // w2 0..15
#define PS(w2, c, l)  scratch[((w2) * 12 + (c)) * 64 + (l)]   // w2 0..15

__global__ void __launch_bounds__(1024) fused_topk_mass_mlp_kernel(
        const float4* __restrict__ P,
        const int* __restrict__ mask,
        const float* __restrict__ W1,
        const float* __restrict__ b1,
        const unsigned short* __restrict__ W2t,
        const float* __restrict__ b2,
        float* __restrict__ out) {
    __shared__ float scratch[16 * 12 * 64];   // 48 KB (vtop, then psum)
    __shared__ float th_s[3][64];             // 768 B
    __shared__ unsigned short hs[64][88];     // 11 KB
    __shared__ float mass_s[3][64];           // 768 B
    __shared__ int wcnt[16];

    const int b    = blockIdx.y;
    const int t0   = blockIdx.x * 64;
    const int tid  = threadIdx.x;
    const int lane = tid & 63;
    const int w    = tid >> 6;                // 0..15
    const bool mb  = mask_is_bytes(mask);

    const bool blockValid = mask_at(mask, mb, b * NT + t0);   // mask monotone

    if (blockValid) {
        // ---- L count: 2048 mask entries / 1024 threads ----
        int cnt = 0;
#pragma unroll
        for (int it = 0; it < 2; ++it) {
            int i = tid + it * 1024;
            cnt += (int)__popcll(__ballot(mask_at(mask, mb, b * NT + i)));
        }
        if (lane == 0) wcnt[w] = cnt;
        __syncthreads();                               // B1

        int L = 0;
#pragma unroll
        for (int j = 0; j < 16; ++j) L += wcnt[j];
        const int C    = (L + 15) >> 4;                // L >= 1024 -> C >= 64
        const int sBeg = w * C;
        const int sEnd = min(sBeg + C, L);

        const float4* __restrict__ Pb = P + b * NT;
        float4 pt = Pb[t0 + lane];                     // coalesced
        float4 a  = make_float4(pt.x, -pt.y, -pt.z, -pt.w);

        const float NEGBIG = -3.402823466e38f;
        float v0 = NEGBIG, v1 = NEGBIG, v2 = NEGBIG, v3 = NEGBIG;
        float v4 = NEGBIG, v5 = NEGBIG, v6 = NEGBIG, v7 = NEGBIG;

        // ---- pass 1: chunk-local top-8 (uniform-address global reads) ----
#pragma unroll 4
        for (int s = sBeg; s < sEnd; ++s) {
            float4 ps = Pb[s];                         // wave-uniform address
            float d = dot4(a, ps);
            INS8(v0, v1, v2, v3, v4, v5, v6, v7, d);
        }
        VT(w, 0, lane) = v0; VT(w, 1, lane) = v1;
        VT(w, 2, lane) = v2; VT(w, 3, lane) = v3;
        VT(w, 4, lane) = v4; VT(w, 5, lane) = v5;
        VT(w, 6, lane) = v6; VT(w, 7, lane) = v7;
        __syncthreads();                               // B2

        // ---- wave 0 merges the other 15 chunks' candidates ----
        if (w == 0) {
            for (int w2 = 1; w2 < 16; ++w2) {
#pragma unroll
                for (int j = 0; j < 8; ++j) {
                    float d = VT(w2, j, lane);         // lane-contiguous
                    INS8(v0, v1, v2, v3, v4, v5, v6, v7, d);
                }
            }
            th_s[0][lane] = v1;   // th2
            th_s[1][lane] = v3;   // th4
            th_s[2][lane] = v7;   // th8
        }
        __syncthreads();                               // B3 (vtop dead)

        const float th2 = th_s[0][lane];
        const float th4 = th_s[1][lane];
        const float th8 = th_s[2][lane];

        // ---- pass 2: exact-membership partial sums ----
        float s2x = 0.f, s2y = 0.f, s2z = 0.f, s2w = 0.f;
        float s4x = 0.f, s4y = 0.f, s4z = 0.f, s4w = 0.f;
        float s8x = 0.f, s8y = 0.f, s8z = 0.f, s8w = 0.f;
#pragma unroll 4
        for (int s = sBeg; s < sEnd; ++s) {
            float4 ps = Pb[s];
            float d = dot4(a, ps);
            if (d >= th8) {
                s8x += ps.x; s8y += ps.y; s8z += ps.z; s8w += ps.w;
                if (d >= th4) {
                    s4x += ps.x; s4y += ps.y; s4z += ps.z; s4w += ps.w;
                    if (d >= th2) {
                        s2x += ps.x; s2y += ps.y; s2z += ps.z; s2w += ps.w;
                    }
                }
            }
        }
        PS(w, 0, lane) = s2x;  PS(w, 1, lane) = s2y;
        PS(w, 2, lane) = s2z;  PS(w, 3, lane) = s2w;
        PS(w, 4, lane) = s4x;  PS(w, 5, lane) = s4y;
        PS(w, 6, lane) = s4z;  PS(w, 7, lane) = s4w;
        PS(w, 8, lane) = s8x;  PS(w, 9, lane) = s8y;
        PS(w, 10, lane) = s8z; PS(w, 11, lane) = s8w;
        __syncthreads();                               // B4

        // ---- first wave: reduce 16 slices + masses ----
        if (tid < 64) {
            float tot[12];
#pragma unroll
            for (int c = 0; c < 12; ++c) {
                float acc = 0.f;
#pragma unroll
                for (int w2 = 0; w2 < 16; ++w2) acc += PS(w2, c, lane);
                tot[c] = acc;
            }
            const bool maskt = (t0 + lane) < L;
            const float MZ = sqrtf(1e-8f);
            auto massf = [&](float sx, float sy, float sz, float sw) -> float {
                float q = sx * sx;
                q = __builtin_fmaf(-sy, sy, q);
                q = __builtin_fmaf(-sz, sz, q);
                q = __builtin_fmaf(-sw, sw, q);
                q = fmaxf(q, 0.f);
                return sqrtf(q + 1e-8f);
            };
            mass_s[0][lane] = maskt ? massf(tot[0], tot[1], tot[2], tot[3]) : MZ;
            mass_s[1][lane] = maskt ? massf(tot[4], tot[5], tot[6], tot[7]) : MZ;
            mass_s[2][lane] = maskt ? massf(tot[8], tot[9], tot[10], tot[11]) : MZ;
        }
    } else {
        if (tid < 64) {
            const float MZ = sqrtf(1e-8f);
            mass_s[0][tid] = MZ;
            mass_s[1][tid] = MZ;
            mass_s[2][tid] = MZ;
        }
    }
    __syncthreads();                                   // B5 (common)

    // ---- h = gelu(mass @ W1 + b1), bf16 -> LDS (4 h per thread) ----
    {
        const int tt = lane;
        const int hr = w;                  // 0..15, wave-uniform
        float q0 = mass_s[0][tt];
        float q1 = mass_s[1][tt];
        float q2 = mass_s[2][tt];
        unsigned short hv[4];
#pragma unroll
        for (int j = 0; j < 4; ++j) {
            int hh = hr * 4 + j;
            float pre = b1[hh];
            pre = __builtin_fmaf(q0, W1[hh], pre);
            pre = __builtin_fmaf(q1, W1[NH + hh], pre);
            pre = __builtin_fmaf(q2, W1[2 * NH + hh], pre);
            float g = 0.5f * pre * (1.0f + erff(pre * 0.70710678118654752f));
            hv[j] = f2bf(g);
        }
        *(uint2*)&hs[tt][hr * 4] = *(const uint2*)hv;  // 8 B, aligned
    }
    __syncthreads();                                   // B6

    // ---- MFMA: out[b*NT + t0 .. +63][0..511] = h @ W2 + b2 ----
    // wave w: m-tile (w&3)*16 (16 tokens), n-slice (w>>2)*128.
    const int col   = lane & 15;
    const int quad  = lane >> 4;
    const int mtile = w & 3;
    const int nBase = (w >> 2) * 128;

    short8 afrag[2];
#pragma unroll
    for (int ks = 0; ks < 2; ++ks)
        afrag[ks] = *(const short8*)&hs[mtile * 16 + col][ks * 32 + quad * 8];

    float4v acc[8];
#pragma unroll
    for (int nt = 0; nt < 8; ++nt)
        acc[nt] = (float4v)(0.f);

#pragma unroll
    for (int nt = 0; nt < 8; ++nt) {
        const unsigned short* wp = W2t + (nBase + nt * 16 + col) * NH + quad * 8;
        short8 bf0 = *(const short8*)(wp);
        short8 bf1 = *(const short8*)(wp + 32);
        acc[nt] = __builtin_amdgcn_mfma_f32_16x16x32_bf16(afrag[0], bf0, acc[nt], 0, 0, 0);
        acc[nt] = __builtin_amdgcn_mfma_f32_16x16x32_bf16(afrag[1], bf1, acc[nt], 0, 0, 0);
    }

#pragma unroll
    for (int nt = 0; nt < 8; ++nt) {
        float bias = b2[nBase + nt * 16 + col];
        int mRow = b * NT + t0 + mtile * 16 + quad * 4;
        size_t base = (size_t)mRow * ND + nBase + nt * 16 + col;
#pragma unroll
        for (int r = 0; r < 4; ++r) {
            out[base + (size_t)r * ND] = acc[nt][r] + bias;
        }
    }
}

extern "C" void kernel_launch(void* const* d_in, const int* in_sizes, int n_in,
                              void* d_out, int out_size, void* d_ws, size_t ws_size,
                              hipStream_t stream) {
    const float* tok  = (const float*)d_in[0];
    const int*   mask = (const int*)d_in[1];   // layout auto-detected in-kernel
    const float* W1   = (const float*)d_in[2];
    const float* b1   = (const float*)d_in[3];
    const float* W2   = (const float*)d_in[4];
    const float* b2   = (const float*)d_in[5];
    float*       out  = (float*)d_out;

    float4*         P   = (float4*)d_ws;                                   // 512 KB
    unsigned short* W2t = (unsigned short*)((char*)d_ws + (size_t)NB * NT * 16);  // 64 KB

    compute_P_kernel<<<dim3(NB * NT / 256), dim3(256), 0, stream>>>(tok, mask, P, W2t, W2);

    dim3 gB(NT / 64, NB);
    fused_topk_mass_mlp_kernel<<<gB, dim3(1024), 0, stream>>>(
        P, mask, W1, b1, W2t, b2, out);
}

// Round 13
// 153.735 us; speedup vs baseline: 1.0653x; 1.0653x over previous
//
#include <hip/hip_runtime.h>
#include <hip/hip_bf16.h>
#include <math.h>

#define NB 16
#define NT 2048
#define ND 512
#define NH 64

typedef __attribute__((ext_vector_type(8))) short short8;
typedef __attribute__((ext_vector_type(4))) float float4v;

__device__ __forceinline__ bool mask_is_bytes(const int* m) {
    return m[0] == 0x01010101;
}
__device__ __forceinline__ bool mask_at(const int* m, bool bytes, int i) {
    if (bytes) return ((const unsigned char*)m)[i] != 0;
    return m[i] != 0;
}

__device__ __forceinline__ unsigned short f2bf(float x) {
    unsigned int u = __float_as_uint(x);
    u += 0x7fffu + ((u >> 16) & 1u);
    return (unsigned short)(u >> 16);
}

// 8-slot sorted-descending insert via med3 chain (exact no-op when D < V7).
#define INS8(V0,V1,V2,V3,V4,V5,V6,V7,D)                          \
    {                                                            \
        float n0 = fmaxf(V0, D);                                 \
        float n1 = __builtin_amdgcn_fmed3f(D, V0, V1);           \
        float n2 = __builtin_amdgcn_fmed3f(D, V1, V2);           \
        float n3 = __builtin_amdgcn_fmed3f(D, V2, V3);           \
        float n4 = __builtin_amdgcn_fmed3f(D, V3, V4);           \
        float n5 = __builtin_amdgcn_fmed3f(D, V4, V5);           \
        float n6 = __builtin_amdgcn_fmed3f(D, V5, V6);           \
        float n7 = __builtin_amdgcn_fmed3f(D, V6, V7);           \
        V0 = n0; V1 = n1; V2 = n2; V3 = n3;                      \
        V4 = n4; V5 = n5; V6 = n6; V7 = n7;                      \
    }

// broadcast lane j's float via v_readlane (exact bits, pure VALU)
__device__ __forceinline__ float rdlane(float v, int j) {
    return __uint_as_float(
        __builtin_amdgcn_readlane(__float_as_uint(v), j));
}

// dot of a (token four-vec, metric folded) with broadcast scalars; explicit
// fmaf so pass 1 / pass 2 recompute bitwise-identical values.
__device__ __forceinline__ float dotb(float4 a, float sE, float sx,
                                      float sy, float sz) {
    float d = a.x * sE;
    d = __builtin_fmaf(a.y, sx, d);
    d = __builtin_fmaf(a.z, sy, d);
    d = __builtin_fmaf(a.w, sz, d);
    return d;
}

// ---------------------------------------------------------------------------
// Kernel A: one-time W2 fp32[k][n] -> bf16 W2t[n][k].
// ---------------------------------------------------------------------------
__global__ void __launch_bounds__(256) w2t_kernel(
        const float* __restrict__ W2, unsigned short* __restrict__ W2t) {
    int i = blockIdx.x * 256 + threadIdx.x;
    int n = i & (ND - 1), k = i >> 9;
    W2t[n * NH + k] = f2bf(W2[k * ND + n]);
}

// ---------------------------------------------------------------------------
// Kernel B: fused (R8 structure; scan loops rewritten readlane-style).
// 512 thr = 8 waves, 64 tokens/block, grid 512 = 2 blocks/CU.
// Scan: ONE coalesced ds_read_b128 per 64 s-values (lane l holds s=sb+l),
// then v_readlane broadcasts each s's 4 components -> dots. LDS scan
// traffic drops 64x vs R8's per-s broadcast reads; cost moves to VALU.
// Chunks padded to x64: masked slots are (-1e30,0,0,0) and self-exclude,
// so no L-clamp needed inside the unrolled loop.
// ---------------------------------------------------------------------------
#define VT(w2, j, l)  scratch[((w2) * 8 + (j)) * 64 + (l)]
#define PS(w2, c, l)  scratch[((w2) * 12 + (c)) * 64 + (l)]

__global__ void __launch_bounds__(512) fused_topk_mass_mlp_kernel(
        const float* __restrict__ tok,
        const int* __restrict__ mask,
        const float* __restrict__ W1,
        const float* __restrict__ b1,
        const unsigned short* __restrict__ W2t,
        const float* __restrict__ b2,
        float* __restrict__ out) {
    __shared__ float Plds[NT * 4];            // 32 KB
    __shared__ float scratch[8 * 12 * 64];    // 24 KB (vtop, then psum)
    __shared__ unsigned short hs[64][88];     // 11 KB
    __shared__ float mass_s[3][64];           // 768 B
    __shared__ int wcnt[8];

    const int b    = blockIdx.y;
    const int t0   = blockIdx.x * 64;
    const int tid  = threadIdx.x;
    const int lane = tid & 63;
    const int w    = tid >> 6;
    const bool mb  = mask_is_bytes(mask);

    const bool blockValid = mask_at(mask, mb, b * NT + t0);   // mask monotone

    if (blockValid) {
        // ---- stage tokens -> P in LDS; count L ----
        int cnt = 0;
#pragma unroll
        for (int it = 0; it < 4; ++it) {
            int i = tid + it * 512;
            float4 tv = ((const float4*)tok)[b * NT + i];
            bool m = mask_at(mask, mb, b * NT + i);
            float E = tv.x, Pt = tv.y, eta = tv.z, phi = tv.w;
            float px = Pt * cosf(phi);
            float py = Pt * sinf(phi);
            float pz = Pt * sinhf(fminf(fmaxf(eta, -20.f), 20.f));
            float4 pv = m ? make_float4(E, px, py, pz)
                          : make_float4(-1e30f, 0.f, 0.f, 0.f);
            *(float4*)&Plds[i * 4] = pv;
            cnt += (int)__popcll(__ballot(m));
        }
        if (lane == 0) wcnt[w] = cnt;
        __syncthreads();                               // B1

        int L = 0;
#pragma unroll
        for (int j = 0; j < 8; ++j) L += wcnt[j];
        // chunk = multiple of 64; 8*C >= L; padded tail entries are masked
        // slots (-1e30,...) which can never be selected.
        const int C    = 64 * ((L + 511) >> 9);
        const int sBeg = w * C;

        float4 pt = *(const float4*)&Plds[(t0 + lane) * 4];
        float4 a  = make_float4(pt.x, -pt.y, -pt.z, -pt.w);

        const float NEGBIG = -3.402823466e38f;
        float v0 = NEGBIG, v1 = NEGBIG, v2 = NEGBIG, v3 = NEGBIG;
        float v4 = NEGBIG, v5 = NEGBIG, v6 = NEGBIG, v7 = NEGBIG;

        // ---- pass 1: chunk-local top-8, readlane-broadcast style ----
        for (int sb = sBeg; sb < sBeg + C; sb += 64) {
            float4 ck = *(const float4*)&Plds[(sb + lane) * 4];  // coalesced
#pragma unroll
            for (int j = 0; j < 64; ++j) {
                float sE = rdlane(ck.x, j);
                float sx = rdlane(ck.y, j);
                float sy = rdlane(ck.z, j);
                float sz = rdlane(ck.w, j);
                float d = dotb(a, sE, sx, sy, sz);
                INS8(v0, v1, v2, v3, v4, v5, v6, v7, d);
            }
        }
        VT(w, 0, lane) = v0; VT(w, 1, lane) = v1;
        VT(w, 2, lane) = v2; VT(w, 3, lane) = v3;
        VT(w, 4, lane) = v4; VT(w, 5, lane) = v5;
        VT(w, 6, lane) = v6; VT(w, 7, lane) = v7;
        __syncthreads();                               // B2

        // ---- merge 64 candidates (all waves, redundant, in-register) ----
        float m0 = NEGBIG, m1 = NEGBIG, m2_ = NEGBIG, m3 = NEGBIG;
        float m4 = NEGBIG, m5 = NEGBIG, m6 = NEGBIG, m7 = NEGBIG;
#pragma unroll
        for (int w2 = 0; w2 < 8; ++w2) {
#pragma unroll
            for (int j = 0; j < 8; ++j) {
                float d = VT(w2, j, lane);
                INS8(m0, m1, m2_, m3, m4, m5, m6, m7, d);
            }
        }
        const float th2 = m1, th4 = m3, th8 = m7;
        __syncthreads();                               // B3 (vtop dead)

        // ---- pass 2: exact-membership partial sums (same readlane form) ----
        float s2x = 0.f, s2y = 0.f, s2z = 0.f, s2w = 0.f;
        float s4x = 0.f, s4y = 0.f, s4z = 0.f, s4w = 0.f;
        float s8x = 0.f, s8y = 0.f, s8z = 0.f, s8w = 0.f;
        for (int sb = sBeg; sb < sBeg + C; sb += 64) {
            float4 ck = *(const float4*)&Plds[(sb + lane) * 4];
#pragma unroll
            for (int j = 0; j < 64; ++j) {
                float sE = rdlane(ck.x, j);
                float sx = rdlane(ck.y, j);
                float sy = rdlane(ck.z, j);
                float sz = rdlane(ck.w, j);
                float d = dotb(a, sE, sx, sy, sz);
                if (d >= th8) {
                    s8x += sE; s8y += sx; s8z += sy; s8w += sz;
                    if (d >= th4) {
                        s4x += sE; s4y += sx; s4z += sy; s4w += sz;
                        if (d >= th2) {
                            s2x += sE; s2y += sx; s2z += sy; s2w += sz;
                        }
                    }
                }
            }
        }
        PS(w, 0, lane) = s2x;  PS(w, 1, lane) = s2y;
        PS(w, 2, lane) = s2z;  PS(w, 3, lane) = s2w;
        PS(w, 4, lane) = s4x;  PS(w, 5, lane) = s4y;
        PS(w, 6, lane) = s4z;  PS(w, 7, lane) = s4w;
        PS(w, 8, lane) = s8x;  PS(w, 9, lane) = s8y;
        PS(w, 10, lane) = s8z; PS(w, 11, lane) = s8w;
        __syncthreads();                               // B4

        // ---- wave 0: reduce + masses ----
        if (w == 0) {
            float tot[12];
#pragma unroll
            for (int c = 0; c < 12; ++c) {
                float acc = 0.f;
#pragma unroll
                for (int w2 = 0; w2 < 8; ++w2) acc += PS(w2, c, lane);
                tot[c] = acc;
            }
            const bool maskt = (t0 + lane) < L;
            const float MZ = sqrtf(1e-8f);
            auto massf = [&](float sx, float sy, float sz, float sw) -> float {
                float q = sx * sx;
                q = __builtin_fmaf(-sy, sy, q);
                q = __builtin_fmaf(-sz, sz, q);
                q = __builtin_fmaf(-sw, sw, q);
                q = fmaxf(q, 0.f);
                return sqrtf(q + 1e-8f);
            };
            mass_s[0][lane] = maskt ? massf(tot[0], tot[1], tot[2], tot[3]) : MZ;
            mass_s[1][lane] = maskt ? massf(tot[4], tot[5], tot[6], tot[7]) : MZ;
            mass_s[2][lane] = maskt ? massf(tot[8], tot[9], tot[10], tot[11]) : MZ;
        }
    } else {
        if (tid < 64) {
            const float MZ = sqrtf(1e-8f);
            mass_s[0][tid] = MZ;
            mass_s[1][tid] = MZ;
            mass_s[2][tid] = MZ;
        }
    }
    __syncthreads();                                   // B5 (common)

    // ---- h = gelu(mass @ W1 + b1), bf16 -> LDS ----
    {
        const int tt = lane;
        const int hr = w;                  // wave-uniform -> W1/b1 scalar loads
        float q0 = mass_s[0][tt];
        float q1 = mass_s[1][tt];
        float q2 = mass_s[2][tt];
        unsigned short hv[8];
#pragma unroll
        for (int j = 0; j < 8; ++j) {
            int hh = hr * 8 + j;
            float pre = b1[hh];
            pre = __builtin_fmaf(q0, W1[hh], pre);
            pre = __builtin_fmaf(q1, W1[NH + hh], pre);
            pre = __builtin_fmaf(q2, W1[2 * NH + hh], pre);
            float g = 0.5f * pre * (1.0f + erff(pre * 0.70710678118654752f));
            hv[j] = f2bf(g);
        }
        *(short8*)&hs[tt][hr * 8] = *(const short8*)hv;
    }
    __syncthreads();                                   // B6

    // ---- MFMA: out[b*NT + t0 .. +63][0..511] = h @ W2 + b2 ----
    const int col   = lane & 15;
    const int quad  = lane >> 4;
    const int mhalf = w >> 2;              // token half (0..1)
    const int nBase = (w & 3) * 128;

    short8 afrag[2][2];
#pragma unroll
    for (int mt = 0; mt < 2; ++mt)
#pragma unroll
        for (int ks = 0; ks < 2; ++ks)
            afrag[mt][ks] = *(const short8*)&hs[mhalf * 32 + mt * 16 + col][ks * 32 + quad * 8];

    float4v acc[2][8];
#pragma unroll
    for (int mt = 0; mt < 2; ++mt)
#pragma unroll
        for (int nt = 0; nt < 8; ++nt)
            acc[mt][nt] = (float4v)(0.f);

#pragma unroll
    for (int nt = 0; nt < 8; ++nt) {
        const unsigned short* wp = W2t + (nBase + nt * 16 + col) * NH + quad * 8;
        short8 bf0 = *(const short8*)(wp);
        short8 bf1 = *(const short8*)(wp + 32);
        acc[0][nt] = __builtin_amdgcn_mfma_f32_16x16x32_bf16(afrag[0][0], bf0, acc[0][nt], 0, 0, 0);
        acc[1][nt] = __builtin_amdgcn_mfma_f32_16x16x32_bf16(afrag[1][0], bf0, acc[1][nt], 0, 0, 0);
        acc[0][nt] = __builtin_amdgcn_mfma_f32_16x16x32_bf16(afrag[0][1], bf1, acc[0][nt], 0, 0, 0);
        acc[1][nt] = __builtin_amdgcn_mfma_f32_16x16x32_bf16(afrag[1][1], bf1, acc[1][nt], 0, 0, 0);
    }

#pragma unroll
    for (int nt = 0; nt < 8; ++nt) {
        float bias = b2[nBase + nt * 16 + col];
#pragma unroll
        for (int mt = 0; mt < 2; ++mt) {
            int mRow = b * NT + t0 + mhalf * 32 + mt * 16 + quad * 4;
            size_t base = (size_t)mRow * ND + nBase + nt * 16 + col;
#pragma unroll
            for (int r = 0; r < 4; ++r) {
                out[base + (size_t)r * ND] = acc[mt][nt][r] + bias;
            }
        }
    }
}

extern "C" void kernel_launch(void* const* d_in, const int* in_sizes, int n_in,
                              void* d_out, int out_size, void* d_ws, size_t ws_size,
                              hipStream_t stream) {
    const float* tok  = (const float*)d_in[0];
    const int*   mask = (const int*)d_in[1];   // layout auto-detected in-kernel
    const float* W1   = (const float*)d_in[2];
    const float* b1   = (const float*)d_in[3];
    const float* W2   = (const float*)d_in[4];
    const float* b2   = (const float*)d_in[5];
    float*       out  = (float*)d_out;

    unsigned short* W2t = (unsigned short*)d_ws;       // 64 KB

    w2t_kernel<<<dim3(ND * NH / 256), dim3(256), 0, stream>>>(W2, W2t);

    dim3 gB(NT / 64, NB);
    fused_topk_mass_mlp_kernel<<<gB, dim3(512), 0, stream>>>(
        tok, mask, W1, b1, W2t, b2, out);
}